// Round 7
// baseline (160.741 us; speedup 1.0000x reference)
//
#include <hip/hip_runtime.h>
#include <hip/hip_bf16.h>
#include <math.h>

#define BATCH 16
#define NPTS 1024
#define DIM 64
#define EPSF 0.1f
#define INV_EPS 10.0f
#define MAX_ITER 100
#define THRESHF 0.1f
#define LSTRIDE 72  // shorts; 64+8 pad keeps b128 LDS reads conflict-cheap

typedef _Float16 h8 __attribute__((ext_vector_type(8)));
typedef _Float16 half2v __attribute__((ext_vector_type(2)));
typedef short short8v __attribute__((ext_vector_type(8)));
typedef float float4v __attribute__((ext_vector_type(4)));

// extract packed half pair P (template => parse-time constant indices)
template <int P>
__device__ __forceinline__ half2v h2get(h8 v) {
  return __builtin_shufflevector(v, v, 2 * P, 2 * P + 1);
}

#define ATOMIC_ST(p, v) \
  __hip_atomic_store((p), (v), __ATOMIC_RELAXED, __HIP_MEMORY_SCOPE_AGENT)
#define ATOMIC_LD(p) \
  __hip_atomic_load((p), __ATOMIC_RELAXED, __HIP_MEMORY_SCOPE_AGENT)

__device__ inline float waveSum(float x) {
#pragma unroll
  for (int off = 32; off; off >>= 1) x += __shfl_xor(x, off, 64);
  return x;
}
__device__ inline float waveMax(float x) {
#pragma unroll
  for (int off = 32; off; off >>= 1) x = fmaxf(x, __shfl_xor(x, off, 64));
  return x;
}
__device__ inline long long packTag(int tag, float v) {
  return ((long long)tag << 32) | (long long)__float_as_uint(v);
}
__device__ inline long long pollTag(long long* p, int tag) {
  long long w;
  do { w = ATOMIC_LD(p); } while ((int)(w >> 32) < tag);
  return w;
}
// dual poll: keep both loads in flight each retry (parallel RTs)
__device__ inline void pollTag2(long long* p0, long long* p1, int tag,
                                float& v0, float& v1) {
  long long a = ATOMIC_LD(p0), b = ATOMIC_LD(p1);
  while ((int)(a >> 32) < tag || (int)(b >> 32) < tag) {
    a = ATOMIC_LD(p0);
    b = ATOMIC_LD(p1);
  }
  v0 = __uint_as_float((unsigned)a);
  v1 = __uint_as_float((unsigned)b);
}

// Round-7: dual-slab (K rows + K^T cols) tagged exchange; no atomics.
// 256 blocks x 512 threads, 1 block/CU. Block kslot of batch
// (blk&7)+8*(blk>>7) owns rows [64k,+64) AND columns [64k,+64).
// Per iteration:
//   PhaseA (rows, K slab): u-update only; publish 64 tagged eu words.
//   poll full eu (2 words/thread; tag==flag==data; 1 RT) -> ahL (x1024 fp16,
//     chunk-padded stride 136 to avoid bank conflicts); barrier.
//   col side (K^T slab): own 64 colsums via dot2 f32-accum + 8-lane reduce;
//     w recurrence in registers; publish 64 tagged w words.
//   poll full w (2 words/thread; 1 RT) -> whL/wLDS; barrier.
// Single-buffer safety: eu(n+1) publish requires w(n) poll passed, which
// requires every col-owner consumed eu(n); w(n+1) publish requires eu(n+1)
// poll passed, which requires every reader consumed w(n). Deltas in
// parity-2 tagged deltaT (leader self-gates errB[n] before its w(n+1)).
// Lag-1 errB global early-stop as before (break before w update: w stays
// at n-1 on stop, eu restored from euPrev).
// Poison-compat (0xAA): tag high words signed (poison<2), errB "<0"
// sentinel, costPart +1.0 bias "<0.5" sentinel.
__global__ __launch_bounds__(512, 2) void sinkhorn_fused(
    const float* __restrict__ x, const float* __restrict__ y,
    __hip_bfloat16* __restrict__ syh,  // [BATCH*NPTS*DIM] bf16 softmax(y)
    __hip_bfloat16* __restrict__ sxh,  // [BATCH*NPTS*DIM] bf16 softmax(x)
    float* __restrict__ y2,            // [BATCH*NPTS]
    float* __restrict__ x2g,           // [BATCH*NPTS]
    long long* __restrict__ euT,       // [BATCH][1024] tagged a_i
    long long* __restrict__ wT,        // [BATCH][1024] tagged w_j
    long long* __restrict__ deltaT,    // [2][BATCH][16] tagged block deltas
    long long* __restrict__ flags,     // [BATCH][16] prologue rendezvous
    float* __restrict__ errB,          // [MAX_ITER][BATCH], sentinel <0
    float* __restrict__ costPart,      // [256], sentinel <0.5
    float* __restrict__ out) {
  __shared__ __attribute__((aligned(16))) short xs[64 * LSTRIDE];
  __shared__ __attribute__((aligned(16))) short ys[2][64 * LSTRIDE];
  __shared__ __attribute__((aligned(16))) short os[2][64 * LSTRIDE];
  __shared__ __attribute__((aligned(16))) float wLDS[NPTS];
  __shared__ __attribute__((aligned(16))) _Float16 whL[NPTS];
  __shared__ __attribute__((aligned(16))) _Float16 ahL[8 * 136];  // padded
  __shared__ float x2L[64];
  __shared__ float derr[8];
  __shared__ float errbL[BATCH];
  const int t = threadIdx.x;
  const int blk = blockIdx.x;
  const int wave = t >> 6, lane = t & 63;
  const int batch = (blk & 7) + 8 * (blk >> 7);
  const int kslot = (blk >> 3) & 15;
  const float log_mu = logf(1.0f / 1024.0f + 1e-8f);
  const float mu_c = 1.0f / 1024.0f + 1e-8f;  // exp(log_mu)

  // ---- Phase 0: softmax. x,y rows -> global (bf16 pairs) + norms. ----
#pragma unroll
  for (int rr = 0; rr < 8; rr++) {
    int rl = wave * 8 + rr;  // 0..63 local row
    int gr = batch * NPTS + kslot * 64 + rl;
    // x row: keep in LDS for K row-slab A-frags, AND publish for K^T builds
    float xv = x[(size_t)gr * DIM + lane];
    float mx = waveMax(xv);
    float ex = __expf(xv - mx);
    float sx = waveSum(ex);
    float px = ex / sx;
    __hip_bfloat16 hbx = (__hip_bfloat16)px;
    xs[rl * LSTRIDE + lane] = *(const short*)&hbx;
    float sqx = waveSum(px * px);
    if (lane == 0) x2L[rl] = sqx;
    unsigned xbits = *(const unsigned short*)&hbx;
    unsigned xnb = __shfl_down(xbits, 1);
    if ((lane & 1) == 0)
      ATOMIC_ST((unsigned*)((unsigned short*)sxh + (size_t)gr * DIM + lane),
                xbits | (xnb << 16));
    if (lane == 0) ATOMIC_ST(&x2g[gr], sqx);
    // y row: publish for whole batch
    float yv = y[(size_t)gr * DIM + lane];
    float my = waveMax(yv);
    float ey = __expf(yv - my);
    float sy = waveSum(ey);
    float py = ey / sy;
    __hip_bfloat16 hby = (__hip_bfloat16)py;
    unsigned bits = *(const unsigned short*)&hby;
    unsigned nb = __shfl_down(bits, 1);
    if ((lane & 1) == 0)
      ATOMIC_ST((unsigned*)((unsigned short*)syh + (size_t)gr * DIM + lane),
                bits | (nb << 16));
    float sqy = waveSum(py * py);
    if (lane == 0) ATOMIC_ST(&y2[gr], sqy);
  }
  __syncthreads();  // vmcnt drain: all publishes at L3
  if (t == 0) ATOMIC_ST(&flags[batch * 16 + kslot], (long long)1 << 32);
  if (t < 16) {
    while ((int)(ATOMIC_LD(&flags[batch * 16 + t]) >> 32) < 1) {}
  }
  __syncthreads();

  // ---- Prologue A: K row-slab (own 64 rows x 1024 cols, fp16) via MFMA ----
  const int m = lane & 15, q = lane >> 4;
  const int g = lane >> 3, sub = lane & 7;
  const int sw = wave & 3, ts = wave >> 2;
  h8 ka[8], kb[8];  // row-slab: row wave*8+rr, cols [8*lane,+8)/[512+8*lane,+8)
  {
    short8v a0 = *(const short8v*)&xs[(sw * 16 + m) * LSTRIDE + q * 8];
    short8v a1 = *(const short8v*)&xs[(sw * 16 + m) * LSTRIDE + 32 + q * 8];
    float xa[4];
#pragma unroll
    for (int reg = 0; reg < 4; reg++) xa[reg] = x2L[sw * 16 + q * 4 + reg];
#pragma unroll
    for (int k = 0; k < 8; k++) {
      {
        int idx = t;
#pragma unroll
        for (int rep = 0; rep < 2; rep++, idx += 512) {
          int r = idx >> 3, c = idx & 7;
          *(short8v*)&ys[r >> 6][(r & 63) * LSTRIDE + c * 8] = *(const short8v*)(
              (const short*)syh + ((size_t)batch * NPTS + 128 * k + r) * DIM + c * 8);
        }
      }
      __syncthreads();
      const int jt = 2 * k + ts;
#pragma unroll
      for (int tj = 0; tj < 4; tj++) {
        short8v b0 = *(const short8v*)&ys[ts][(tj * 16 + m) * LSTRIDE + q * 8];
        short8v b1 = *(const short8v*)&ys[ts][(tj * 16 + m) * LSTRIDE + 32 + q * 8];
        float4v c = {0.f, 0.f, 0.f, 0.f};
        c = __builtin_amdgcn_mfma_f32_16x16x32_bf16(a0, b0, c, 0, 0, 0);
        c = __builtin_amdgcn_mfma_f32_16x16x32_bf16(a1, b1, c, 0, 0, 0);
        float y2v = y2[(size_t)batch * NPTS + jt * 64 + tj * 16 + m];
#pragma unroll
        for (int reg = 0; reg < 4; reg++) {
          float C = xa[reg] + y2v - 2.0f * c[reg];
          _Float16 kv = (_Float16)__expf(-INV_EPS * C);
          os[ts][(sw * 16 + q * 4 + reg) * LSTRIDE + tj * 16 + m] = *(const short*)&kv;
        }
      }
      __syncthreads();
      {
        int e0 = (2 * k) & 7, e1 = (2 * k + 1) & 7;
        if (g == e0 || g == e1) {
          const short* srcp = (g == e0) ? &os[0][0] : &os[1][0];
#pragma unroll
          for (int rr = 0; rr < 8; rr++) {
            h8 v = *(const h8*)&srcp[(wave * 8 + rr) * LSTRIDE + sub * 8];
            if (k < 4) ka[rr] = v; else kb[rr] = v;
          }
        }
      }
      __syncthreads();
    }
  }

  // ---- Prologue B: K^T col-slab (own 64 cols x 1024 rows, fp16) ----
  // kt[j] (j 0..15): col (t>>3)+64*kslot, rows [(t&7)*128 + 8j, +8) pairs.
  h8 kt[16];
  {
    // reload xs with OWN softmaxed y rows (A operand of the transposed build)
    {
      int r = t >> 3, c8 = t & 7;
      *(short8v*)&xs[r * LSTRIDE + c8 * 8] = *(const short8v*)(
          (const short*)syh + ((size_t)batch * NPTS + kslot * 64 + r) * DIM + c8 * 8);
    }
    __syncthreads();
    short8v a0 = *(const short8v*)&xs[(sw * 16 + m) * LSTRIDE + q * 8];
    short8v a1 = *(const short8v*)&xs[(sw * 16 + m) * LSTRIDE + 32 + q * 8];
    float yn[4];
#pragma unroll
    for (int reg = 0; reg < 4; reg++)
      yn[reg] = y2[(size_t)batch * NPTS + kslot * 64 + sw * 16 + q * 4 + reg];
#pragma unroll
    for (int k = 0; k < 8; k++) {
      {  // stage 128 softmax-x rows
        int idx = t;
#pragma unroll
        for (int rep = 0; rep < 2; rep++, idx += 512) {
          int r = idx >> 3, c = idx & 7;
          *(short8v*)&ys[r >> 6][(r & 63) * LSTRIDE + c * 8] = *(const short8v*)(
              (const short*)sxh + ((size_t)batch * NPTS + 128 * k + r) * DIM + c * 8);
        }
      }
      __syncthreads();
      const int jt = 2 * k + ts;
#pragma unroll
      for (int tj = 0; tj < 4; tj++) {
        short8v b0 = *(const short8v*)&ys[ts][(tj * 16 + m) * LSTRIDE + q * 8];
        short8v b1 = *(const short8v*)&ys[ts][(tj * 16 + m) * LSTRIDE + 32 + q * 8];
        float4v c = {0.f, 0.f, 0.f, 0.f};
        c = __builtin_amdgcn_mfma_f32_16x16x32_bf16(a0, b0, c, 0, 0, 0);
        c = __builtin_amdgcn_mfma_f32_16x16x32_bf16(a1, b1, c, 0, 0, 0);
        float x2v = x2g[(size_t)batch * NPTS + jt * 64 + tj * 16 + m];
#pragma unroll
        for (int reg = 0; reg < 4; reg++) {
          float C = yn[reg] + x2v - 2.0f * c[reg];  // |y_c - x_r|^2
          _Float16 kv = (_Float16)__expf(-INV_EPS * C);
          os[ts][(sw * 16 + q * 4 + reg) * LSTRIDE + tj * 16 + m] = *(const short*)&kv;
        }
      }
      __syncthreads();
      if ((t & 7) == k) {  // this thread's 128-row chunk == this k-step
        int c = t >> 3;
#pragma unroll
        for (int j = 0; j < 8; j++)
          kt[j] = *(const h8*)&os[0][c * LSTRIDE + j * 8];
#pragma unroll
        for (int j = 0; j < 8; j++)
          kt[8 + j] = *(const h8*)&os[1][c * LSTRIDE + j * 8];
      }
      __syncthreads();
    }
  }

  for (int j = t; j < NPTS; j += 512) {
    wLDS[j] = 1.f;
    whL[j] = (_Float16)1.f;
  }
  __syncthreads();

  float eu[8], euPrev[8];  // a_i = exp(u/eps) for rows wave*8+rr
#pragma unroll
  for (int r = 0; r < 8; r++) eu[r] = 1.f;
  float wj = 1.f;  // w for own column (t>>3), replicated over 8 lanes
  int it = 0;
  long long* euB = &euT[((size_t)batch << 10)];
  long long* wB = &wT[((size_t)batch << 10)];

  while (true) {
#pragma unroll
    for (int r = 0; r < 8; r++) euPrev[r] = eu[r];
    // ---- Phase A (rows): u update only (col work moved to K^T side) ----
    {
      h8 wh0 = *(const h8*)&whL[8 * lane];
      h8 wh1 = *(const h8*)&whL[512 + 8 * lane];
      float delta = 0.f;
#pragma unroll
      for (int rr = 0; rr < 8; rr++) {
        float d0 = 0.f, d1 = 0.f;
#define DOT_STEP(P)                                                         \
  d0 = __builtin_amdgcn_fdot2(h2get<P>(ka[rr]), h2get<P>(wh0), d0, false);  \
  d1 = __builtin_amdgcn_fdot2(h2get<P>(kb[rr]), h2get<P>(wh1), d1, false);
        DOT_STEP(0) DOT_STEP(1) DOT_STEP(2) DOT_STEP(3)
#undef DOT_STEP
        float dot = waveSum(d0 + d1);
        float sp = eu[rr] * dot + 1e-6f;
        float lg = __logf(sp);
        delta += fabsf(EPSF * (log_mu - lg));  // == |u_new - u_old|
        eu[rr] = mu_c * eu[rr] * __builtin_amdgcn_rcpf(sp);
      }
      if (lane == 0) derr[wave] = delta;
      // publish own 64 rows' a values (tagged; fire-and-forget)
      long long* ep = &euB[kslot * 64 + wave * 8];
#pragma unroll
      for (int rr = 0; rr < 8; rr++)
        if (lane == rr) ATOMIC_ST(&ep[rr], packTag(it + 2, eu[rr]));
    }
    // lag-1 errB retrieval (overlaps the eu gate; almost always ready)
    if (it >= 1 && t < BATCH) {
      float v;
      while ((v = ATOMIC_LD(&errB[(it - 1) * BATCH + t])) < 0.f) {}
      errbL[t] = v;
    }
    // ---- gate 1: poll full a vector (tag==flag==data, 1 RT) ----
    {
      float a0v, a1v;
      pollTag2(&euB[t], &euB[t + 512], it + 2, a0v, a1v);
      ahL[t + ((t >> 7) << 3)] = (_Float16)(a0v * 1024.0f);
      int r1 = t + 512;
      ahL[r1 + ((r1 >> 7) << 3)] = (_Float16)(a1v * 1024.0f);
    }
    __syncthreads();  // B1: ahL + derr + errbL visible
    if (t == 0) {
      float e = 0.f;
#pragma unroll
      for (int w = 0; w < 8; w++) e += derr[w];
      ATOMIC_ST(&deltaT[((it & 1) * BATCH + batch) * 16 + kslot],
                packTag(it + 2, e));
    }
    // ---- lag-1 global stop (w/wj still at iteration it-1 here) ----
    if (it >= 1) {
      float errv = 0.f;
#pragma unroll
      for (int k = 0; k < BATCH; k++) errv += errbL[k];
      if (errv * (1.0f / (float)BATCH) < THRESHF) {
        // reference stopped after body it-1: undo this iteration's u update
#pragma unroll
        for (int r = 0; r < 8; r++) eu[r] = euPrev[r];
        break;
      }
    }
    // ---- col side (K^T): own 64 colsums + w recurrence, local only ----
    {
      const h8* av = (const h8*)&ahL[136 * (t & 7)];
      float c0 = 0.f, c1 = 0.f, c2 = 0.f, c3 = 0.f;
#define CDOT(J, ACC)                                                        \
  {                                                                         \
    h8 kv = kt[J], a8 = av[J];                                              \
    ACC = __builtin_amdgcn_fdot2(h2get<0>(kv), h2get<0>(a8), ACC, false);   \
    ACC = __builtin_amdgcn_fdot2(h2get<1>(kv), h2get<1>(a8), ACC, false);   \
    ACC = __builtin_amdgcn_fdot2(h2get<2>(kv), h2get<2>(a8), ACC, false);   \
    ACC = __builtin_amdgcn_fdot2(h2get<3>(kv), h2get<3>(a8), ACC, false);   \
  }
      CDOT(0, c0) CDOT(1, c1) CDOT(2, c2) CDOT(3, c3)
      CDOT(4, c0) CDOT(5, c1) CDOT(6, c2) CDOT(7, c3)
      CDOT(8, c0) CDOT(9, c1) CDOT(10, c2) CDOT(11, c3)
      CDOT(12, c0) CDOT(13, c1) CDOT(14, c2) CDOT(15, c3)
#undef CDOT
      float cd = (c0 + c1) + (c2 + c3);
      cd += __shfl_xor(cd, 1, 64);
      cd += __shfl_xor(cd, 2, 64);
      cd += __shfl_xor(cd, 4, 64);  // all 8 lanes of the col group have cd
      // cd = 1024 * colsum; fold the 2^-10 exactly
      float sp = wj * cd * 0.0009765625f + 1e-6f;
      wj = mu_c * wj * __builtin_amdgcn_rcpf(sp);
      if ((lane & 7) == 0)
        ATOMIC_ST(&wB[kslot * 64 + (t >> 3)], packTag(it + 2, wj));
    }
    // leader aggregates deltas -> errB[it] (overlaps the w gate; leader
    // self-gates: its w(it+1) publish follows, so parity-2 deltaT is safe)
    if (kslot == 0 && wave == 0) {
      float e16 = 0.f;
      if (lane < 16)
        e16 = __uint_as_float((unsigned)pollTag(
            &deltaT[((it & 1) * BATCH + batch) * 16 + lane], it + 2));
#pragma unroll
      for (int off = 8; off; off >>= 1) e16 += __shfl_xor(e16, off, 16);
      if (lane == 0) ATOMIC_ST(&errB[it * BATCH + batch], e16);
    }
    // ---- gate 2: poll full w vector (1 RT) ----
    {
      float w0v, w1v;
      pollTag2(&wB[t], &wB[t + 512], it + 2, w0v, w1v);
      wLDS[t] = w0v;
      whL[t] = (_Float16)w0v;
      wLDS[t + 512] = w1v;
      whL[t + 512] = (_Float16)w1v;
    }
    it++;
    if (it >= MAX_ITER) break;
    __syncthreads();  // B2: whL visible before next Phase A
  }

  // ---- Final cost: pi = a_i*K*w_j, C = -eps*log(K) (row slab) ----
  {
    __syncthreads();
    const float4* w4 = (const float4*)wLDS;
    float wreg[16];
    *(float4*)&wreg[0]  = w4[2 * lane];
    *(float4*)&wreg[4]  = w4[2 * lane + 1];
    *(float4*)&wreg[8]  = w4[128 + 2 * lane];
    *(float4*)&wreg[12] = w4[128 + 2 * lane + 1];
    float csum = 0.f;
#pragma unroll
    for (int rr = 0; rr < 8; rr++) {
      float ai = eu[rr];  // == exp(u/eps)
#pragma unroll
      for (int n = 0; n < 8; n++) {
        float kf = (float)ka[rr][n];
        if (kf > 0.f) csum += ai * wreg[n] * kf * (-EPSF * __logf(kf));
        float kg = (float)kb[rr][n];
        if (kg > 0.f) csum += ai * wreg[8 + n] * kg * (-EPSF * __logf(kg));
      }
    }
    csum = waveSum(csum);
    if (lane == 0) derr[wave] = csum;
    __syncthreads();
    if (t == 0) {
      float cst = 0.f;
#pragma unroll
      for (int w = 0; w < 8; w++) cst += derr[w];
      ATOMIC_ST(&costPart[blk], cst + 1.0f);  // bias: sentinel-safe vs poison
    }
    // block 0 gathers all 256 partials and writes the scalar output
    if (blk == 0) {
      float* gb = (float*)&ys[0][0];
      if (t < 256) {
        float v;
        while ((v = ATOMIC_LD(&costPart[t])) < 0.5f) {}
        gb[t] = v;
      }
      __syncthreads();
      if (wave == 0) {
        float s = gb[lane] + gb[lane + 64] + gb[lane + 128] + gb[lane + 192];
        s = waveSum(s);
        if (lane == 0) out[0] = (s - 256.0f) * (1.0f / (float)BATCH);
      }
    }
  }
}

extern "C" void kernel_launch(void* const* d_in, const int* in_sizes, int n_in,
                              void* d_out, int out_size, void* d_ws,
                              size_t ws_size, hipStream_t stream) {
  (void)in_sizes; (void)n_in; (void)out_size; (void)ws_size;
  const float* x = (const float*)d_in[0];
  const float* y = (const float*)d_in[1];
  float* out = (float*)d_out;

  char* ws = (char*)d_ws;
  size_t off = 0;
  auto alloc = [&](size_t nbytes) -> void* {
    void* p = (void*)(ws + off);
    off = (off + nbytes + 255) & ~(size_t)255;
    return p;
  };
  __hip_bfloat16* syh = (__hip_bfloat16*)alloc((size_t)BATCH * NPTS * DIM * 2);
  __hip_bfloat16* sxh = (__hip_bfloat16*)alloc((size_t)BATCH * NPTS * DIM * 2);
  float* y2 = (float*)alloc((size_t)BATCH * NPTS * 4);
  float* x2g = (float*)alloc((size_t)BATCH * NPTS * 4);
  long long* euT = (long long*)alloc((size_t)BATCH * NPTS * 8);
  long long* wT = (long long*)alloc((size_t)BATCH * NPTS * 8);
  long long* deltaT = (long long*)alloc((size_t)2 * BATCH * 16 * 8);
  long long* flags = (long long*)alloc((size_t)BATCH * 16 * 8);
  float* errB = (float*)alloc((size_t)MAX_ITER * BATCH * 4);
  float* costPart = (float*)alloc(256 * 4);

  void* args[] = {&x, &y, &syh, &sxh, &y2, &x2g, &euT, &wT,
                  &deltaT, &flags, &errB, &costPart, &out};
  hipLaunchCooperativeKernel((void*)sinkhorn_fused, dim3(256), dim3(512), args,
                             0, stream);
}

// Round 8
// 125.194 us; speedup vs baseline: 1.2839x; 1.2839x over previous
//
#include <hip/hip_runtime.h>
#include <hip/hip_bf16.h>
#include <math.h>

#define BATCH 16
#define NPTS 1024
#define DIM 64
#define EPSF 0.1f
#define INV_EPS 10.0f
#define MAX_ITER 100
#define THRESHF 0.1f
#define LSTRIDE 72  // shorts; 64+8 pad keeps b128 LDS reads conflict-cheap

typedef _Float16 h8 __attribute__((ext_vector_type(8)));
typedef _Float16 half2v __attribute__((ext_vector_type(2)));
typedef short short8v __attribute__((ext_vector_type(8)));
typedef float float4v __attribute__((ext_vector_type(4)));

// extract packed half pair P (template => parse-time constant indices)
template <int P>
__device__ __forceinline__ half2v h2get(h8 v) {
  return __builtin_shufflevector(v, v, 2 * P, 2 * P + 1);
}

#define ATOMIC_ST(p, v) \
  __hip_atomic_store((p), (v), __ATOMIC_RELAXED, __HIP_MEMORY_SCOPE_AGENT)
#define ATOMIC_LD(p) \
  __hip_atomic_load((p), __ATOMIC_RELAXED, __HIP_MEMORY_SCOPE_AGENT)

__device__ inline float waveSum(float x) {
#pragma unroll
  for (int off = 32; off; off >>= 1) x += __shfl_xor(x, off, 64);
  return x;
}
__device__ inline float waveMax(float x) {
#pragma unroll
  for (int off = 32; off; off >>= 1) x = fmaxf(x, __shfl_xor(x, off, 64));
  return x;
}

// Single fused cooperative kernel: softmax + K-build (MFMA, K in registers)
// + Sinkhorn loop + cost. 256 blocks x 512 threads, 1 block/CU.
// Block owns rows [kslot*64,+64) of batch (blk&7)+8*(blk>>7).
//
// Round-8 = round-5 (best measured: 55.4us/dispatch) + T14 async-stage
// prologue: each K-build step issues step k+1's global loads into registers
// BEFORE step k's MFMA/expf section and writes them to LDS after the
// barrier -> L3 load latency hides under compute; 3->2 barriers/step.
// No cross-block protocol changes (restructures regressed 0/4: R3/R6/R7).
//  - K resident as packed fp16 (h8 ka[8],kb[8]); consumed by
//    v_dot2_f32_f16 (row dots, f32 accum) and v_pk_fma_f16 (col partials).
//  - column partials accumulated scaled by 1024 (ai*1024) to keep fp16
//    normal; the 2^10 scale folds bit-exactly into Phase B:
//    w' = mu*w*rcp(w*cs' + 1e-6*1024)*1024  ==  mu*w*rcp(w*cs + 1e-6).
//  - w kept f32 in wLDS (recurrence); fp16 copy whL feeds Phase A.
// Exchange (round-2 protocol, best measured): staggered f32 atomicAdd
// colsum[3] triple-buffer, 64-bit flags tag<<32|delta, lag-1 errB stop.
// Poison-compat (0xAA): flag tag high-word signed (poison < 1), errB "< 0"
// sentinel, costPart +1.0 bias with "< 0.5" sentinel, colsum zeroed before
// first use. Cross-block data via relaxed agent-scope ops (L3 coherence
// point); ordering = __syncthreads vmcnt drain + monotonic flags.
__global__ __launch_bounds__(512, 2) void sinkhorn_fused(
    const float* __restrict__ x, const float* __restrict__ y,
    __hip_bfloat16* __restrict__ syh,  // [BATCH*NPTS*DIM] bf16
    float* __restrict__ y2,            // [BATCH*NPTS]
    float* __restrict__ colsum,        // [3][BATCH][NPTS] (scaled x1024)
    long long* __restrict__ flags,     // [BATCH][16]: tag<<32 | delta bits
    float* __restrict__ errB,          // [MAX_ITER][BATCH], sentinel <0
    float* __restrict__ costPart,      // [256], sentinel <0.5
    float* __restrict__ out) {
  __shared__ __attribute__((aligned(16))) short xs[64 * LSTRIDE];
  __shared__ __attribute__((aligned(16))) short ys[2][64 * LSTRIDE];
  __shared__ __attribute__((aligned(16))) short os[2][64 * LSTRIDE];
  __shared__ __attribute__((aligned(16))) float wLDS[NPTS];
  __shared__ __attribute__((aligned(16))) _Float16 whL[NPTS];
  __shared__ __attribute__((aligned(16))) float colpart[8][NPTS];
  __shared__ float x2L[64];
  __shared__ float derr[8];
  __shared__ float errbL[BATCH];
  const int t = threadIdx.x;
  const int blk = blockIdx.x;
  const int wave = t >> 6, lane = t & 63;
  const int batch = (blk & 7) + 8 * (blk >> 7);
  const int kslot = (blk >> 3) & 15;
  const float log_mu = logf(1.0f / 1024.0f + 1e-8f);
  const float mu_c = 1.0f / 1024.0f + 1e-8f;  // exp(log_mu)

  // ---- Phase 0: softmax. x-rows -> LDS only; y-rows -> global via sc1. ----
#pragma unroll
  for (int rr = 0; rr < 8; rr++) {
    int rl = wave * 8 + rr;  // 0..63 local row
    int gr = batch * NPTS + kslot * 64 + rl;
    // x row (consumed only by this block: keep in LDS)
    float xv = x[(size_t)gr * DIM + lane];
    float mx = waveMax(xv);
    float ex = __expf(xv - mx);
    float sx = waveSum(ex);
    float px = ex / sx;
    __hip_bfloat16 hbx = (__hip_bfloat16)px;
    xs[rl * LSTRIDE + lane] = *(const short*)&hbx;
    float sqx = waveSum(px * px);
    if (lane == 0) x2L[rl] = sqx;
    // y row (consumed by whole batch: publish write-through to L3)
    float yv = y[(size_t)gr * DIM + lane];
    float my = waveMax(yv);
    float ey = __expf(yv - my);
    float sy = waveSum(ey);
    float py = ey / sy;
    __hip_bfloat16 hby = (__hip_bfloat16)py;
    unsigned bits = *(const unsigned short*)&hby;
    unsigned nb = __shfl_down(bits, 1);
    if ((lane & 1) == 0)
      ATOMIC_ST((unsigned*)((unsigned short*)syh + (size_t)gr * DIM + lane),
                bits | (nb << 16));
    float sqy = waveSum(py * py);
    if (lane == 0) ATOMIC_ST(&y2[gr], sqy);
  }
  // zero own colsum slices of all 3 buffers (before any peer can add)
  if (t < 192) {
    int buf = t >> 6, j = kslot * 64 + (t & 63);
    ATOMIC_ST(&colsum[((size_t)buf * BATCH + batch) * NPTS + j], 0.f);
  }
  __syncthreads();  // vmcnt drain: all sc1 stores complete at L3
  if (t == 0) ATOMIC_ST(&flags[batch * 16 + kslot], (long long)1 << 32);
  if (t < 16) {
    while ((int)(ATOMIC_LD(&flags[batch * 16 + t]) >> 32) < 1) {}
  }
  __syncthreads();

  // ---- Prologue: build K slab (64x1024, packed fp16) via MFMA ----
  // T14 async-stage: prefetch step k+1's 16KB into regs before step k's
  // MFMA/expf; ds_write after the barrier. 2 barriers/step (was 3).
  const int m = lane & 15, q = lane >> 4;
  const int g = lane >> 3, sub = lane & 7;
  const int sw = wave & 3, ts = wave >> 2;
  short8v a0 = *(const short8v*)&xs[(sw * 16 + m) * LSTRIDE + q * 8];
  short8v a1 = *(const short8v*)&xs[(sw * 16 + m) * LSTRIDE + 32 + q * 8];
  float xa[4];
#pragma unroll
  for (int reg = 0; reg < 4; reg++) xa[reg] = x2L[sw * 16 + q * 4 + reg];
  h8 ka[8], kb[8];  // K row-slab: cols [8*lane,+8) and [512+8*lane,+8)
  {
    const int r0 = t >> 3, c0 = (t & 7) * 8;
    const int r1 = (t + 512) >> 3, c1 = ((t + 512) & 7) * 8;
    const short* syb = (const short*)syh + (size_t)batch * NPTS * DIM;
    short8v pf0 = *(const short8v*)(syb + (size_t)r0 * DIM + c0);
    short8v pf1 = *(const short8v*)(syb + (size_t)r1 * DIM + c1);
    *(short8v*)&ys[r0 >> 6][(r0 & 63) * LSTRIDE + c0] = pf0;
    *(short8v*)&ys[r1 >> 6][(r1 & 63) * LSTRIDE + c1] = pf1;
    __syncthreads();  // stage 0 visible
#pragma unroll
    for (int k = 0; k < 8; k++) {
      if (k < 7) {  // issue next-stage loads; flight hides under MFMA+expf
        pf0 = *(const short8v*)(syb + (size_t)(128 * (k + 1) + r0) * DIM + c0);
        pf1 = *(const short8v*)(syb + (size_t)(128 * (k + 1) + r1) * DIM + c1);
      }
      const int jt = 2 * k + ts;
      float4v accv[4];
#pragma unroll
      for (int tj = 0; tj < 4; tj++) {
        short8v b0 = *(const short8v*)&ys[ts][(tj * 16 + m) * LSTRIDE + q * 8];
        short8v b1 = *(const short8v*)&ys[ts][(tj * 16 + m) * LSTRIDE + 32 + q * 8];
        float4v c = {0.f, 0.f, 0.f, 0.f};
        c = __builtin_amdgcn_mfma_f32_16x16x32_bf16(a0, b0, c, 0, 0, 0);
        c = __builtin_amdgcn_mfma_f32_16x16x32_bf16(a1, b1, c, 0, 0, 0);
        accv[tj] = c;
      }
#pragma unroll
      for (int tj = 0; tj < 4; tj++) {
        float y2v = y2[(size_t)batch * NPTS + jt * 64 + tj * 16 + m];
#pragma unroll
        for (int reg = 0; reg < 4; reg++) {
          float C = xa[reg] + y2v - 2.0f * accv[tj][reg];
          _Float16 kv = (_Float16)__expf(-INV_EPS * C);
          os[ts][(sw * 16 + q * 4 + reg) * LSTRIDE + tj * 16 + m] = *(const short*)&kv;
        }
      }
      __syncthreads();  // os visible; ys(k) fully consumed
      {
        int e0 = (2 * k) & 7, e1 = (2 * k + 1) & 7;
        if (g == e0 || g == e1) {
          const short* srcp = (g == e0) ? &os[0][0] : &os[1][0];
#pragma unroll
          for (int rr = 0; rr < 8; rr++) {
            h8 v = *(const h8*)&srcp[(wave * 8 + rr) * LSTRIDE + sub * 8];
            if (k < 4) ka[rr] = v; else kb[rr] = v;
          }
        }
      }
      if (k < 7) {  // ys(k) consumed above the barrier -> safe to overwrite
        *(short8v*)&ys[r0 >> 6][(r0 & 63) * LSTRIDE + c0] = pf0;
        *(short8v*)&ys[r1 >> 6][(r1 & 63) * LSTRIDE + c1] = pf1;
      }
      __syncthreads();  // ys(k+1) visible; os consumed before next overwrite
    }
  }

  for (int j = t; j < NPTS; j += 512) {
    wLDS[j] = 1.f;
    whL[j] = (_Float16)1.f;
  }
  __syncthreads();

  float eu[8], euPrev[8];  // eu = exp(u/eps); u never materialized
#pragma unroll
  for (int r = 0; r < 8; r++) eu[r] = 1.f;
  int it = 0;

  while (true) {
#pragma unroll
    for (int r = 0; r < 8; r++) euPrev[r] = eu[r];
    // ---- Phase A: u update + column partials (packed fp16) ----
    h8 wh0 = *(const h8*)&whL[8 * lane];        // cols [8*lane, +8)
    h8 wh1 = *(const h8*)&whL[512 + 8 * lane];  // cols [512+8*lane, +8)
    half2v c0[4], c1[4];  // scaled column partials (x1024), fp16
#pragma unroll
    for (int p = 0; p < 4; p++) {
      c0[p] = half2v{(_Float16)0.f, (_Float16)0.f};
      c1[p] = half2v{(_Float16)0.f, (_Float16)0.f};
    }
    float delta = 0.f;
#pragma unroll
    for (int rr = 0; rr < 8; rr++) {
      float d0 = 0.f, d1 = 0.f;
#define DOT_STEP(P)                                                         \
  d0 = __builtin_amdgcn_fdot2(h2get<P>(ka[rr]), h2get<P>(wh0), d0, false);  \
  d1 = __builtin_amdgcn_fdot2(h2get<P>(kb[rr]), h2get<P>(wh1), d1, false);
      DOT_STEP(0) DOT_STEP(1) DOT_STEP(2) DOT_STEP(3)
#undef DOT_STEP
      float dot = waveSum(d0 + d1);
      float sp = eu[rr] * dot + 1e-6f;
      float lg = __logf(sp);
      delta += fabsf(EPSF * (log_mu - lg));  // == |u_new - u_old|
      float ai = mu_c * eu[rr] * __builtin_amdgcn_rcpf(sp);  // exp(u_new/eps)
      eu[rr] = ai;
      _Float16 aih = (_Float16)(ai * 1024.0f);  // scaled: keeps fp16 normal
      half2v ai2 = {aih, aih};
#define FMA_STEP(P)                                 \
  c0[P] = h2get<P>(ka[rr]) * ai2 + c0[P];           \
  c1[P] = h2get<P>(kb[rr]) * ai2 + c1[P];
      FMA_STEP(0) FMA_STEP(1) FMA_STEP(2) FMA_STEP(3)
#undef FMA_STEP
    }
    if (lane == 0) derr[wave] = delta;
    {
      float4* cp = (float4*)&colpart[wave][0];
      cp[2 * lane] = make_float4((float)c0[0][0], (float)c0[0][1],
                                 (float)c0[1][0], (float)c0[1][1]);
      cp[2 * lane + 1] = make_float4((float)c0[2][0], (float)c0[2][1],
                                     (float)c0[3][0], (float)c0[3][1]);
      cp[128 + 2 * lane] = make_float4((float)c1[0][0], (float)c1[0][1],
                                       (float)c1[1][0], (float)c1[1][1]);
      cp[128 + 2 * lane + 1] = make_float4((float)c1[2][0], (float)c1[2][1],
                                           (float)c1[3][0], (float)c1[3][1]);
    }
    __syncthreads();  // S1: colpart visible
    // block partial -> f32 atomicAdd into L3 colsum, STAGGERED by kslot so
    // concurrent blocks' bursts hit disjoint cache lines (no same-line
    // atomic serialization; coverage/values identical).
    float* cs = colsum + ((size_t)(it % 3) * BATCH + batch) * NPTS;
    {
      int j0 = (t + (kslot << 6)) & 1023;
      int j1 = j0 ^ 512;
      float s0 = 0.f, s1 = 0.f;
#pragma unroll
      for (int w = 0; w < 8; w++) { s0 += colpart[w][j0]; s1 += colpart[w][j1]; }
      unsafeAtomicAdd(&cs[j0], s0);
      unsafeAtomicAdd(&cs[j1], s1);
    }
    // pre-drain window: lag-1 errB retry overlaps the atomic ack
    if (it >= 1 && t < BATCH) {
      float v;
      while ((v = ATOMIC_LD(&errB[(it - 1) * BATCH + t])) < 0.f) {}
      errbL[t] = v;
    }
    float eblk = 0.f;
    if (t == 0) {
#pragma unroll
      for (int w = 0; w < 8; w++) eblk += derr[w];
    }
    __syncthreads();  // S2: vmcnt drain (atomics at L3) + errbL visible
    if (t == 0)
      ATOMIC_ST(&flags[batch * 16 + kslot],
                ((long long)(it + 2) << 32) | (long long)__float_as_uint(eblk));
    // ---- lag-1 global stop check (err of previous iteration) ----
    if (it >= 1) {
      float errv = 0.f;
#pragma unroll
      for (int k = 0; k < BATCH; k++) errv += errbL[k];
      if (errv * (1.0f / (float)BATCH) < THRESHF) {
        // reference stopped after body it-1: undo this iteration's u update
#pragma unroll
        for (int r = 0; r < 8; r++) eu[r] = euPrev[r];
        break;
      }
    }
    // poll peers' flags; the same word carries their deltas
    float dpoll = 0.f;
    if (t < 16) {
      long long fw;
      while ((int)((fw = ATOMIC_LD(&flags[batch * 16 + t])) >> 32) < it + 2) {}
      dpoll = __uint_as_float((unsigned)fw);
    }
    __syncthreads();  // S3: all threads past poll
    // column-sum loads first (critical path; values final per flags)
    float cs0 = ATOMIC_LD(&cs[t]);
    float cs1 = ATOMIC_LD(&cs[t + 512]);
    // zero the buffer for iteration it+2 (race-free: peers' it-1 reads done
    // before they flagged it+2; first adds to it occur after it+2's poll)
    if (t < 64)
      ATOMIC_ST(&colsum[((size_t)((it + 2) % 3) * BATCH + batch) * NPTS +
                        kslot * 64 + t], 0.f);
    // batch err for iteration it: shfl-reduce the 16 polled deltas (wave 0);
    // kslot==0 leader publishes for the cross-batch lag-1 check.
    if (wave == 0) {
      float e16 = (lane < 16) ? dpoll : 0.f;
#pragma unroll
      for (int off = 8; off; off >>= 1) e16 += __shfl_xor(e16, off, 16);
      if (t == 0 && kslot == 0) ATOMIC_ST(&errB[it * BATCH + batch], e16);
    }
    // ---- Phase B: w update, multiplicative, 1024-scale folded bit-exactly:
    // mu*w*rcp(w*cs' + 1e-6*1024)*1024 == mu*w*rcp(w*(cs'/1024) + 1e-6) ----
    {
      float w0 = wLDS[t];
      float wn0 = mu_c * w0 *
                  __builtin_amdgcn_rcpf(w0 * cs0 + (1e-6f * 1024.0f)) * 1024.0f;
      wLDS[t] = wn0;
      whL[t] = (_Float16)wn0;
      float w1 = wLDS[t + 512];
      float wn1 = mu_c * w1 *
                  __builtin_amdgcn_rcpf(w1 * cs1 + (1e-6f * 1024.0f)) * 1024.0f;
      wLDS[t + 512] = wn1;
      whL[t + 512] = (_Float16)wn1;
    }
    it++;
    if (it >= MAX_ITER) break;
    __syncthreads();  // S4: wLDS/whL writes visible before next phase A reads
  }

  // ---- Final cost: pi = a_i*K*w_j, C = -eps*log(K) ----
  {
    __syncthreads();
    const float4* w4 = (const float4*)wLDS;
    float wreg[16];
    *(float4*)&wreg[0]  = w4[2 * lane];
    *(float4*)&wreg[4]  = w4[2 * lane + 1];
    *(float4*)&wreg[8]  = w4[128 + 2 * lane];
    *(float4*)&wreg[12] = w4[128 + 2 * lane + 1];
    float csum = 0.f;
#pragma unroll
    for (int rr = 0; rr < 8; rr++) {
      float ai = eu[rr];  // == exp(u/eps)
#pragma unroll
      for (int n = 0; n < 8; n++) {
        float kf = (float)ka[rr][n];
        if (kf > 0.f)
          csum += ai * wreg[n] * kf * (-EPSF * __logf(kf));
        float kg = (float)kb[rr][n];
        if (kg > 0.f)
          csum += ai * wreg[8 + n] * kg * (-EPSF * __logf(kg));
      }
    }
    csum = waveSum(csum);
    if (lane == 0) derr[wave] = csum;
    __syncthreads();
    if (t == 0) {
      float cst = 0.f;
#pragma unroll
      for (int w = 0; w < 8; w++) cst += derr[w];
      ATOMIC_ST(&costPart[blk], cst + 1.0f);  // bias: sentinel-safe vs poison
    }
    // block 0 gathers all 256 partials and writes the scalar output
    if (blk == 0) {
      if (t < 256) {
        float v;
        while ((v = ATOMIC_LD(&costPart[t])) < 0.5f) {}
        colpart[0][t] = v;
      }
      __syncthreads();
      if (wave == 0) {
        float s = colpart[0][lane] + colpart[0][lane + 64] +
                  colpart[0][lane + 128] + colpart[0][lane + 192];
        s = waveSum(s);
        if (lane == 0) out[0] = (s - 256.0f) * (1.0f / (float)BATCH);
      }
    }
  }
}

extern "C" void kernel_launch(void* const* d_in, const int* in_sizes, int n_in,
                              void* d_out, int out_size, void* d_ws,
                              size_t ws_size, hipStream_t stream) {
  (void)in_sizes; (void)n_in; (void)out_size; (void)ws_size;
  const float* x = (const float*)d_in[0];
  const float* y = (const float*)d_in[1];
  float* out = (float*)d_out;

  char* ws = (char*)d_ws;
  size_t off = 0;
  auto alloc = [&](size_t nbytes) -> void* {
    void* p = (void*)(ws + off);
    off = (off + nbytes + 255) & ~(size_t)255;
    return p;
  };
  __hip_bfloat16* syh = (__hip_bfloat16*)alloc((size_t)BATCH * NPTS * DIM * 2);
  float* y2 = (float*)alloc((size_t)BATCH * NPTS * 4);
  float* colsum = (float*)alloc((size_t)3 * BATCH * NPTS * 4);
  long long* flags = (long long*)alloc((size_t)BATCH * 16 * 8);
  float* errB = (float*)alloc((size_t)MAX_ITER * BATCH * 4);
  float* costPart = (float*)alloc(256 * 4);

  void* args[] = {&x, &y, &syh, &y2, &colsum, &flags,
                  &errB, &costPart, &out};
  hipLaunchCooperativeKernel((void*)sinkhorn_fused, dim3(256), dim3(512), args,
                             0, stream);
}